// Round 13
// baseline (779.591 us; speedup 1.0000x reference)
//
#include <hip/hip_runtime.h>
#include <hip/hip_bf16.h>

#define LFULL 8192
#define HDIM 1024
#define KPAD 8448  // 66 chunks of 128 elems (last 2 chunks zeros)
#define USTRIDE 8320   // elements per Us row: 128 zero-pad + 8192 data
#define UCHUNKS 1040   // uint4 chunks per Us row (= USTRIDE/8)
#define CSTR2 2080     // ring copy stride bytes: 2048 data + 16 dup + 16 pad

typedef __attribute__((ext_vector_type(8))) short bf16x8;
typedef __attribute__((ext_vector_type(4))) float f32x4;
typedef __attribute__((ext_vector_type(16))) float f32x16;

union U16 {
  uint4 u;
  bf16x8 s;
  ushort e[8];
};

__device__ __forceinline__ ushort f2bf(float x) {
  union { float f; uint u; } a;
  a.f = x;
  uint r = a.u + 0x7fffu + ((a.u >> 16) & 1u);
  return (ushort)(r >> 16);
}
__device__ __forceinline__ float bf2f(ushort x) {
  union { uint u; float f; } a;
  a.u = ((uint)x) << 16;
  return a.f;
}

__device__ __forceinline__ void gload16(const void* src, void* lds) {
  __builtin_amdgcn_global_load_lds(
      (const __attribute__((address_space(1))) unsigned int*)src,
      (__attribute__((address_space(3))) unsigned int*)lds, 16, 0, 0);
}

// 4-bit XOR swizzle for Us 16B-chunk index (bijective: low4 ^= bits7:4)
#define USWZ16(cI) ((cI) ^ (((cI) >> 4) & 15))

// ---------------------------------------------------------------------------
// Kernel 1: multi-scale kernel synthesis + L2 norm -> bf16 kbrev[h][8448]
// kbrev[h][x] = k_norm[h][8191-x], zeros for x >= 8192.
// ---------------------------------------------------------------------------
__global__ __launch_bounds__(256) void k_synth_kernel(
    const float* __restrict__ kern, ushort* __restrict__ kout) {
  const int h = blockIdx.x;
  const int tid = threadIdx.x;
  __shared__ float Kw[8][64];
  __shared__ __align__(16) float kv[LFULL];
  __shared__ float red[8];
  for (int idx = tid; idx < 8 * 64; idx += 256) {
    int i = idx >> 6, j = idx & 63;
    Kw[i][j] = kern[(i * HDIM + h) * 64 + j];
  }
  __syncthreads();
  const float mult = (float)(1.0 + 3.0 * (double)h / 1023.0);
  float pw[8];
  pw[7] = 1.0f;
#pragma unroll
  for (int i = 6; i >= 0; --i) pw[i] = pw[i + 1] * mult;
  float ss = 0.0f;
  for (int m = tid; m < LFULL; m += 256) {
    const int i = (m < 64) ? 0 : (32 - __clz(m >> 6));
    const int slog = (i == 0) ? 0 : (i - 1);
    const float inv_s = 1.0f / (float)(1 << slog);
    const int off = (i == 0) ? 0 : (64 << (i - 1));
    const int t = m - off;
    const float pos = ((float)t + 0.5f) * inv_s - 0.5f;
    const float lof = floorf(pos);
    const float wgt = pos - lof;
    int lo = (int)lof;
    int hi = lo + 1;
    lo = min(63, max(0, lo));
    hi = min(63, max(0, hi));
    const float val = (Kw[i][lo] * (1.0f - wgt) + Kw[i][hi] * wgt) * pw[i];
    kv[m] = val;
    ss += val * val;
  }
#pragma unroll
  for (int o = 32; o > 0; o >>= 1) ss += __shfl_xor(ss, o, 64);
  if ((tid & 63) == 0) red[tid >> 6] = ss;
  __syncthreads();
  if (tid == 0) red[0] = sqrtf(red[0] + red[1] + red[2] + red[3]);
  __syncthreads();
  const float inv_norm = 1.0f / red[0];
  ushort* krow = kout + (size_t)h * KPAD;
  for (int m = tid; m < LFULL; m += 256) krow[8191 - m] = f2bf(kv[m] * inv_norm);
  if (tid < 256) krow[8192 + tid] = 0;
}

// ---------------------------------------------------------------------------
// Kernel 2: causal conv via block-Toeplitz 32x32x16 MFMA, T=128 blocks.
// Grid 1024 (1 h). Block: 4 waves (wave = b). acc = 2 F x 4 rg (128 AGPR).
// A-windows from a SHARED 4-phase-copy LDS ring at 4-element granularity:
// copy c holds element x at byte 2(x+4c) mod 2048 (stride 2080B). Lane's
// copy (c32+1)&3 is constant; window start is 8B-aligned -> window = two
// ds_read_b64, no alignbyte/select VALU. Wave w maintains copy w with ONE
// 4B ds_write/step whose value comes from a global load pre-shifted by -4w
// elements (phase shift via source address). Ring is 8 chunks deep; chunk
// 58-d is written at step d and first read at step d+5, slot-collision-free
// for skew<=1 -> lgkmcnt(0)+s_barrier only every 2nd step (32 drains vs 64).
// ---------------------------------------------------------------------------
__global__ __launch_bounds__(256, 2) void conv_mfma_kernel(
    const float* __restrict__ u, const ushort* __restrict__ kbrev,
    const float* __restrict__ Dp, ushort* __restrict__ g) {
  __shared__ __align__(16) ushort Us[4 * USTRIDE];     // 66.5 KB
  __shared__ __align__(16) ushort RingC[4 * (CSTR2 / 2)];  // 8320 B
  const int tid = threadIdx.x;
  const int h = blockIdx.x;
  const int w = tid >> 6;  // wave index == b
  const int lane = tid & 63;
  const int c32 = lane & 31;
  const int qh = lane >> 5;
  uint4* Us4 = (uint4*)Us;
  char* ringB = (char*)RingC;
  const int wbase = w * UCHUNKS + 16;  // chunk base of row data (16 pad chunks)

  // ---- zero pads (4 rows x 16 chunks) ----
  if (tid < 64) Us4[(tid >> 4) * UCHUNKS + (tid & 15)] = make_uint4(0, 0, 0, 0);
  // ---- stage u: fp32 -> bf16, XOR16-swizzled 16B chunks (4 rows) ----
  for (int cc = tid; cc < 4096; cc += 256) {
    const int row = cc >> 10, cI = cc & 1023;
    const float* up = u + (((size_t)(row * HDIM + h)) << 13) + (cI << 3);
    const float4 v0 = *(const float4*)up;
    const float4 v1 = *(const float4*)(up + 4);
    U16 pk;
    pk.e[0] = f2bf(v0.x); pk.e[1] = f2bf(v0.y);
    pk.e[2] = f2bf(v0.z); pk.e[3] = f2bf(v0.w);
    pk.e[4] = f2bf(v1.x); pk.e[5] = f2bf(v1.y);
    pk.e[6] = f2bf(v1.z); pk.e[7] = f2bf(v1.w);
    Us4[(row * UCHUNKS + 16) + USWZ16(cI)] = pk.u;
  }

  // ---- ring prologue: preload chunks 59..65 into copy w ----
  const ushort* kr = kbrev + (size_t)h * KPAD;
  char* ringW = ringB + w * CSTR2;
#pragma unroll
  for (int cn = 59; cn <= 65; ++cn) {
    const uint kv = *(const uint*)(kr + cn * 128 + 2 * lane - 4 * w);
    const int offw = (256 * cn + 4 * lane) & 2047;
    *(uint*)(ringW + offw) = kv;
    if (offw < 16) *(uint*)(ringW + offw + 2048) = kv;
  }
  // prefetch chunk 58 (written at step 0)
  uint kreg = *(const uint*)(kr + 58 * 128 + 2 * lane - 4 * w);
  __syncthreads();

  f32x16 acc[2][4];
#pragma unroll
  for (int f = 0; f < 2; ++f)
#pragma unroll
    for (int rg = 0; rg < 4; ++rg)
#pragma unroll
      for (int q = 0; q < 16; ++q) acc[f][rg][q] = 0.0f;

  const int PBASE = 8191 - c32 + 8 * qh;
  const int cpy = (c32 + 1) & 3;            // lane's phase copy
  const char* ringR = ringB + cpy * CSTR2;
  int BD = 2 * (PBASE + 16 + 4 * cpy);      // byte addr of window mm=7, d=0

  uint4 WA[8], WB[8];
#pragma unroll
  for (int i = 0; i < 8; ++i) WB[i] = make_uint4(0, 0, 0, 0);

// window i (mm=i+7): elements P..P+7 at bytes (BD-32i)..+15, 8B-aligned
#define RD_W(i, DST) {                                                  \
    const int a_ = (BD - 32 * (i)) & 2047;                              \
    const uint2 lo_ = *(const uint2*)(ringR + a_);                      \
    const uint2 hi_ = *(const uint2*)(ringR + a_ + 8);                  \
    (DST) = make_uint4(lo_.x, lo_.y, hi_.x, hi_.y); }

// carried(mm<7) lives in the OTHER bank at [mm+1]; fresh(mm>=7) at [mm-7]
#define FPART(DD, F, WFRESH, WCARR) {                                   \
    const int j0 = (F) * 32 + c32 - (DD);                               \
    const int jc = j0 < 0 ? -1 : j0;                                    \
    const int pb = jc << 4;                                             \
    const int px = jc & 15;                                             \
    _Pragma("unroll")                                                   \
    for (int ks = 0; ks < 8; ++ks) {                                    \
      const int t = 2 * ks + qh;                                        \
      U16 bb;                                                           \
      bb.u = Us4[wbase + pb + (t ^ px)];                                \
      U16 a0, a1, a2, a3;                                               \
      a0.u = (8 - ks >= 7) ? WFRESH[1 - ks] : WCARR[9 - ks];            \
      a1.u = (10 - ks >= 7) ? WFRESH[3 - ks] : WCARR[11 - ks];          \
      a2.u = (12 - ks >= 7) ? WFRESH[5 - ks] : WCARR[13 - ks];          \
      a3.u = WFRESH[7 - ks];                                            \
      acc[F][0] = __builtin_amdgcn_mfma_f32_32x32x16_bf16(a0.s, bb.s, acc[F][0], 0, 0, 0); \
      acc[F][1] = __builtin_amdgcn_mfma_f32_32x32x16_bf16(a1.s, bb.s, acc[F][1], 0, 0, 0); \
      acc[F][2] = __builtin_amdgcn_mfma_f32_32x32x16_bf16(a2.s, bb.s, acc[F][2], 0, 0, 0); \
      acc[F][3] = __builtin_amdgcn_mfma_f32_32x32x16_bf16(a3.s, bb.s, acc[F][3], 0, 0, 0); \
    } }

#define STEP(DD, WFRESH, WCARR, HASF0, DOSYNC) {                        \
    _Pragma("unroll")                                                   \
    for (int i = 0; i < 8; ++i) RD_W(i, WFRESH[i]);                     \
    {                                                                   \
      const int cw = (58 - (DD)) < 0 ? 0 : (58 - (DD));                 \
      const int offw = (((cw & 7) << 8) + 4 * lane) & 2047;             \
      *(uint*)(ringW + offw) = kreg;                                    \
      if (offw < 16) *(uint*)(ringW + offw + 2048) = kreg;              \
      const int cn = (57 - (DD)) < 0 ? 0 : (57 - (DD));                 \
      kreg = *(const uint*)(kr + cn * 128 + 2 * lane - 4 * w);          \
    }                                                                   \
    if (HASF0) { FPART(DD, 0, WFRESH, WCARR); FPART(DD, 1, WFRESH, WCARR); } \
    else { FPART(DD, 1, WFRESH, WCARR); }                               \
    BD -= 256;                                                          \
    if (DOSYNC) {                                                       \
      asm volatile("s_waitcnt lgkmcnt(0)" ::: "memory");                \
      __builtin_amdgcn_s_barrier();                                     \
      __builtin_amdgcn_sched_barrier(0);                                \
    }                                                                   \
  }

  for (int dd = 0; dd < 32; dd += 2) {
    STEP(dd, WA, WB, true, false);
    STEP(dd + 1, WB, WA, true, true);
  }
  for (int dd = 32; dd < 64; dd += 2) {
    STEP(dd, WA, WB, false, false);
    STEP(dd + 1, WB, WA, false, true);
  }

  // ---- epilogue: += D*u, exact GELU, bf16 store ----
  const float Dh = Dp[h];
  ushort* gp = g + (((size_t)(w * HDIM + h)) << 13);
  const ushort* urow = Us + w * USTRIDE + 128;
#pragma unroll
  for (int f = 0; f < 2; ++f) {
#pragma unroll
    for (int rg = 0; rg < 4; ++rg) {
      const int lbase = (f * 32 + c32) * 128 + rg * 32 + 4 * qh;
#pragma unroll
      for (int rq = 0; rq < 4; ++rq) {
        const int l = lbase + 8 * rq;
        const int cI = l >> 3;
        const int phys = USWZ16(cI);
        const uint2 uv = *(const uint2*)(urow + (phys << 3) + 4 * qh);
        float uu[4];
        uu[0] = bf2f((ushort)(uv.x & 0xffff));
        uu[1] = bf2f((ushort)(uv.x >> 16));
        uu[2] = bf2f((ushort)(uv.y & 0xffff));
        uu[3] = bf2f((ushort)(uv.y >> 16));
        ushort o[4];
#pragma unroll
        for (int jj = 0; jj < 4; ++jj) {
          const float y = acc[f][rg][rq * 4 + jj] + Dh * uu[jj];
          const float ge = 0.5f * y * (1.0f + erff(y * 0.70710678118654752f));
          o[jj] = f2bf(ge);
        }
        uint2 op;
        op.x = (uint)o[0] | ((uint)o[1] << 16);
        op.y = (uint)o[2] | ((uint)o[3] << 16);
        *(uint2*)(gp + l) = op;
      }
    }
  }
}

// ---------------------------------------------------------------------------
// Kernel 3: transpose g[b][h][l] -> gt[b][l][h] (64x64 tiles, XOR-swizzled)
// ---------------------------------------------------------------------------
__global__ __launch_bounds__(256) void transpose_kernel(
    const ushort* __restrict__ g, ushort* __restrict__ gt) {
  __shared__ __align__(16) ushort Ts[64 * 64];
  const int l0 = blockIdx.x * 64, hh0 = blockIdx.y * 64, b = blockIdx.z;
  const int tid = threadIdx.x;
#pragma unroll
  for (int p = 0; p < 2; ++p) {
    const int hh = (tid >> 3) + 32 * p;
    const int c8 = tid & 7;
    const uint4 v = *(const uint4*)(g + (((size_t)(b * HDIM + hh0 + hh)) << 13)
                                    + l0 + c8 * 8);
    ((uint4*)Ts)[hh * 8 + (c8 ^ ((hh >> 3) & 7))] = v;
  }
  __syncthreads();
#pragma unroll
  for (int p = 0; p < 2; ++p) {
    const int lr = (tid >> 3) + 32 * p;
    const int o8 = tid & 7;
    U16 pk;
#pragma unroll
    for (int j = 0; j < 8; ++j) {
      const int hq = o8 * 8 + j;
      pk.e[j] = Ts[hq * 64 + (((lr >> 3) ^ o8) << 3) + (lr & 7)];
    }
    ((uint4*)(gt + ((size_t)b * LFULL + l0 + lr) * HDIM + hh0))[o8] = pk.u;
  }
}

// ---------------------------------------------------------------------------
// Kernel 4: W fp32 -> bf16
// ---------------------------------------------------------------------------
__global__ __launch_bounds__(256) void wcvt_kernel(const float* __restrict__ W,
                                                   ushort* __restrict__ Wb) {
  const int i = (blockIdx.x * 256 + threadIdx.x) * 8;
  const float4 v0 = *(const float4*)(W + i);
  const float4 v1 = *(const float4*)(W + i + 4);
  U16 pk;
  pk.e[0] = f2bf(v0.x); pk.e[1] = f2bf(v0.y);
  pk.e[2] = f2bf(v0.z); pk.e[3] = f2bf(v0.w);
  pk.e[4] = f2bf(v1.x); pk.e[5] = f2bf(v1.y);
  pk.e[6] = f2bf(v1.z); pk.e[7] = f2bf(v1.w);
  ((uint4*)Wb)[i >> 3] = pk.u;
}

// ---------------------------------------------------------------------------
// Kernel 5: out[b,o,l] = bo[o] + sum_h Wb[o,h]*gt[b,l,h]  (128x128 MFMA GEMM)
// ---------------------------------------------------------------------------
__global__ __launch_bounds__(256, 2) void outmm_kernel(
    const ushort* __restrict__ Wb, const ushort* __restrict__ gt,
    const float* __restrict__ bo, float* __restrict__ out) {
  __shared__ __align__(16) ushort As[128 * 32];
  __shared__ __align__(16) ushort Bs[128 * 32];
  const int tid = threadIdx.x;
  const int l0 = blockIdx.x * 128, o0 = blockIdx.y * 128, b = blockIdx.z;
  const int w = tid >> 6, lane = tid & 63;
  const int wm = w >> 1, wn = w & 1;
  const int col = lane & 15, q = lane >> 4;
  const int srow = lane >> 2, scol = (lane & 3) * 8;
  f32x4 acc[4][4];
#pragma unroll
  for (int m = 0; m < 4; ++m)
#pragma unroll
    for (int n = 0; n < 4; ++n) acc[m][n] = (f32x4){0.f, 0.f, 0.f, 0.f};
  const ushort* gb = gt + ((size_t)b * LFULL) * HDIM;
  for (int kt = 0; kt < 32; ++kt) {
    const int k0 = kt * 32;
    const int r0 = w * 32;
#pragma unroll
    for (int ii = 0; ii < 2; ++ii) {
      const int ra = r0 + ii * 16 + srow;
      gload16(Wb + (size_t)(o0 + ra) * HDIM + k0 + scol,
              As + (r0 + ii * 16) * 32);
      gload16(gb + (size_t)(l0 + ra) * HDIM + k0 + scol,
              Bs + (r0 + ii * 16) * 32);
    }
    __syncthreads();
    bf16x8 aa[4], bb[4];
#pragma unroll
    for (int m = 0; m < 4; ++m) {
      aa[m] = ((const bf16x8*)As)[(wm * 64 + m * 16 + col) * 4 + q];
      bb[m] = ((const bf16x8*)Bs)[(wn * 64 + m * 16 + col) * 4 + q];
    }
#pragma unroll
    for (int m = 0; m < 4; ++m)
#pragma unroll
      for (int n = 0; n < 4; ++n)
        acc[m][n] = __builtin_amdgcn_mfma_f32_16x16x32_bf16(aa[m], bb[n],
                                                            acc[m][n], 0, 0, 0);
    __syncthreads();
  }
#pragma unroll
  for (int m = 0; m < 4; ++m) {
    const int ob = o0 + wm * 64 + m * 16 + q * 4;
    const float4 bv = *(const float4*)(bo + ob);
    const float bva[4] = {bv.x, bv.y, bv.z, bv.w};
#pragma unroll
    for (int n = 0; n < 4; ++n) {
      const int l = l0 + wn * 64 + n * 16 + col;
      float* op = out + (((size_t)(b * HDIM + ob)) << 13) + l;
#pragma unroll
      for (int v = 0; v < 4; ++v) op[(size_t)v << 13] = acc[m][n][v] + bva[v];
    }
  }
}

// ---------------------------------------------------------------------------
extern "C" void kernel_launch(void* const* d_in, const int* in_sizes, int n_in,
                              void* d_out, int out_size, void* d_ws,
                              size_t ws_size, hipStream_t stream) {
  const float* u = (const float*)d_in[0];     // (4, 1024, 8192)
  const float* kern = (const float*)d_in[1];  // (8, 1, 1024, 64)
  const float* D = (const float*)d_in[2];     // (1, 1024)
  const float* W = (const float*)d_in[3];     // (1024, 1024)
  const float* bo = (const float*)d_in[4];    // (1024,)
  float* out = (float*)d_out;                 // (4, 1024, 8192)

  char* ws = (char*)d_ws;
  ushort* g = (ushort*)ws;                                 // [0, 64 MiB)
  ushort* gt = (ushort*)(ws + ((size_t)64 << 20));         // [64, 128 MiB)
  ushort* kbrev = (ushort*)(ws + ((size_t)128 << 20));     // 1024*8448*2 = 16.5 MiB
  ushort* Wb = (ushort*)(ws + ((size_t)128 << 20));        // reuses kbrev region

  k_synth_kernel<<<HDIM, 256, 0, stream>>>(kern, kbrev);
  conv_mfma_kernel<<<HDIM, 256, 0, stream>>>(u, kbrev, D, g);
  // kbrev dead from here; Wb overlays it.
  wcvt_kernel<<<512, 256, 0, stream>>>(W, Wb);
  transpose_kernel<<<dim3(128, 16, 4), 256, 0, stream>>>(g, gt);
  outmm_kernel<<<dim3(64, 8, 4), 256, 0, stream>>>(Wb, gt, bo, out);
}

// Round 14
// 461.719 us; speedup vs baseline: 1.6885x; 1.6885x over previous
//
#include <hip/hip_runtime.h>
#include <hip/hip_bf16.h>

#define LFULL 8192
#define HDIM 1024
#define KPAD 8448  // 66 chunks of 128 elems (last 2 chunks zeros)
#define USTRIDE 8320   // elements per Us row: 128 zero-pad + 8192 data
#define UCHUNKS 1040   // uint4 chunks per Us row (= USTRIDE/8)
#define CSTRIDE 1040   // ring copy stride in bytes (1024 + 16 pad: 4-bank shift)

typedef __attribute__((ext_vector_type(8))) short bf16x8;
typedef __attribute__((ext_vector_type(4))) float f32x4;
typedef __attribute__((ext_vector_type(16))) float f32x16;

union U16 {
  uint4 u;
  bf16x8 s;
  ushort e[8];
};

__device__ __forceinline__ ushort f2bf(float x) {
  union { float f; uint u; } a;
  a.f = x;
  uint r = a.u + 0x7fffu + ((a.u >> 16) & 1u);
  return (ushort)(r >> 16);
}
__device__ __forceinline__ float bf2f(ushort x) {
  union { uint u; float f; } a;
  a.u = ((uint)x) << 16;
  return a.f;
}

__device__ __forceinline__ void gload16(const void* src, void* lds) {
  __builtin_amdgcn_global_load_lds(
      (const __attribute__((address_space(1))) unsigned int*)src,
      (__attribute__((address_space(3))) unsigned int*)lds, 16, 0, 0);
}

__device__ __forceinline__ uint ALIGNB(uint hi, uint lo, uint sh) {
#if __has_builtin(__builtin_amdgcn_alignbyte)
  return __builtin_amdgcn_alignbyte(hi, lo, sh);
#else
  return (uint)((((unsigned long long)hi << 32) | (unsigned long long)lo) >> (8u * sh));
#endif
}

// 4-bit XOR swizzle for Us 16B-chunk index (bijective: low4 ^= bits7:4)
#define USWZ16(cI) ((cI) ^ (((cI) >> 4) & 15))

// ---------------------------------------------------------------------------
// Kernel 1: multi-scale kernel synthesis + L2 norm -> bf16 kbrev[h][8448]
// kbrev[h][x] = k_norm[h][8191-x], zeros for x >= 8192.
// ---------------------------------------------------------------------------
__global__ __launch_bounds__(256) void k_synth_kernel(
    const float* __restrict__ kern, ushort* __restrict__ kout) {
  const int h = blockIdx.x;
  const int tid = threadIdx.x;
  __shared__ float Kw[8][64];
  __shared__ __align__(16) float kv[LFULL];
  __shared__ float red[8];
  for (int idx = tid; idx < 8 * 64; idx += 256) {
    int i = idx >> 6, j = idx & 63;
    Kw[i][j] = kern[(i * HDIM + h) * 64 + j];
  }
  __syncthreads();
  const float mult = (float)(1.0 + 3.0 * (double)h / 1023.0);
  float pw[8];
  pw[7] = 1.0f;
#pragma unroll
  for (int i = 6; i >= 0; --i) pw[i] = pw[i + 1] * mult;
  float ss = 0.0f;
  for (int m = tid; m < LFULL; m += 256) {
    const int i = (m < 64) ? 0 : (32 - __clz(m >> 6));
    const int slog = (i == 0) ? 0 : (i - 1);
    const float inv_s = 1.0f / (float)(1 << slog);
    const int off = (i == 0) ? 0 : (64 << (i - 1));
    const int t = m - off;
    const float pos = ((float)t + 0.5f) * inv_s - 0.5f;
    const float lof = floorf(pos);
    const float wgt = pos - lof;
    int lo = (int)lof;
    int hi = lo + 1;
    lo = min(63, max(0, lo));
    hi = min(63, max(0, hi));
    const float val = (Kw[i][lo] * (1.0f - wgt) + Kw[i][hi] * wgt) * pw[i];
    kv[m] = val;
    ss += val * val;
  }
#pragma unroll
  for (int o = 32; o > 0; o >>= 1) ss += __shfl_xor(ss, o, 64);
  if ((tid & 63) == 0) red[tid >> 6] = ss;
  __syncthreads();
  if (tid == 0) red[0] = sqrtf(red[0] + red[1] + red[2] + red[3]);
  __syncthreads();
  const float inv_norm = 1.0f / red[0];
  ushort* krow = kout + (size_t)h * KPAD;
  for (int m = tid; m < LFULL; m += 256) krow[8191 - m] = f2bf(kv[m] * inv_norm);
  if (tid < 256) krow[8192 + tid] = 0;
}

// ---------------------------------------------------------------------------
// Kernel 2: causal conv via block-Toeplitz 32x32x16 MFMA, T=128 blocks.
// EXACT R9 structure (best measured: 349 us, MfmaUtil 56%). Grid 1024 (1 h).
// Block: 4 waves (wave = b). acc = 2 F x 4 rg (128 AGPR). A-windows from a
// SHARED 8-phase-copy LDS ring (stride 1040 B, 4-bank shift per copy,
// conflict-free); window = ONE aligned ds_read_b128. Causal zeros via
// 128-elem zero pad before each Us row. WA/WB bank swap carries 6 windows.
// One lgkmcnt(0)+s_barrier per step.
// ---------------------------------------------------------------------------
__global__ __launch_bounds__(256, 2) void conv_mfma_kernel(
    const float* __restrict__ u, const ushort* __restrict__ kbrev,
    const float* __restrict__ Dp, ushort* __restrict__ g) {
  __shared__ __align__(16) ushort Us[4 * USTRIDE];   // 66.5 KB (pad+data x4)
  __shared__ __align__(16) ushort RingC[8 * 520];    // 8320 B: 8 phase copies
  const int tid = threadIdx.x;
  const int h = blockIdx.x;
  const int w = tid >> 6;  // wave index == b
  const int lane = tid & 63;
  const int c32 = lane & 31;
  const int qh = lane >> 5;
  uint4* Us4 = (uint4*)Us;
  char* ringB = (char*)RingC;
  const int wbase = w * UCHUNKS + 16;  // chunk base of row data (16 pad chunks)

  // ---- zero pads (4 rows x 16 chunks) ----
  if (tid < 64) Us4[(tid >> 4) * UCHUNKS + (tid & 15)] = make_uint4(0, 0, 0, 0);
  // ---- stage u: fp32 -> bf16, XOR16-swizzled 16B chunks (4 rows) ----
  for (int cc = tid; cc < 4096; cc += 256) {
    const int row = cc >> 10, cI = cc & 1023;
    const float* up = u + (((size_t)(row * HDIM + h)) << 13) + (cI << 3);
    const float4 v0 = *(const float4*)up;
    const float4 v1 = *(const float4*)(up + 4);
    U16 pk;
    pk.e[0] = f2bf(v0.x); pk.e[1] = f2bf(v0.y);
    pk.e[2] = f2bf(v0.z); pk.e[3] = f2bf(v0.w);
    pk.e[4] = f2bf(v1.x); pk.e[5] = f2bf(v1.y);
    pk.e[6] = f2bf(v1.z); pk.e[7] = f2bf(v1.w);
    Us4[(row * UCHUNKS + 16) + USWZ16(cI)] = pk.u;
  }

  // ---- ring prologue: preload chunks 62,63,64 into copies 2w, 2w+1 ----
  const ushort* kr = kbrev + (size_t)h * KPAD;
  char* ringE = ringB + (2 * w) * CSTRIDE;
  char* ringO = ringB + (2 * w + 1) * CSTRIDE;
#pragma unroll
  for (int cn = 62; cn <= 64; ++cn) {
    const int x0 = 128 * cn + 2 * lane;
    const uint kEp = *(const uint*)(kr + x0);
    const uint kMp = *(const uint*)(kr + x0 - 2);
    const int off = (2 * x0 + 4 * w) & 1023;
    *(uint*)(ringE + off) = kEp;
    *(uint*)(ringO + off) = ALIGNB(kEp, kMp, 2);
  }
  // prefetch chunk 61 (written at step 0)
  uint kE = *(const uint*)(kr + 61 * 128 + 2 * lane);
  uint kM = *(const uint*)(kr + 61 * 128 + 2 * lane - 2);
  __syncthreads();

  f32x16 acc[2][4];
#pragma unroll
  for (int f = 0; f < 2; ++f)
#pragma unroll
    for (int rg = 0; rg < 4; ++rg)
#pragma unroll
      for (int q = 0; q < 16; ++q) acc[f][rg][q] = 0.0f;

  const int PBASE = 8191 - c32 + 8 * qh;
  const int sph = (c32 + 1) & 7;            // lane's phase copy
  const char* ringR = ringB + sph * CSTRIDE;
  int bd = 2 * (PBASE + sph) + 256;         // off(d,mm) = (bd - 32mm) & 1023

  uint4 WA[8], WB[8];
#pragma unroll
  for (int i = 0; i < 8; ++i) WB[i] = make_uint4(0, 0, 0, 0);

// carried(mm<7) lives in the OTHER bank at [mm+1]; fresh(mm>=7) at [mm-7]
#define FPART(DD, F, WFRESH, WCARR) {                                   \
    const int j0 = (F) * 32 + c32 - (DD);                               \
    const int jc = j0 < 0 ? -1 : j0;                                    \
    const int pb = jc << 4;                                             \
    const int px = jc & 15;                                             \
    _Pragma("unroll")                                                   \
    for (int ks = 0; ks < 8; ++ks) {                                    \
      const int t = 2 * ks + qh;                                        \
      U16 bb;                                                           \
      bb.u = Us4[wbase + pb + (t ^ px)];                                \
      U16 a0, a1, a2, a3;                                               \
      a0.u = (8 - ks >= 7) ? WFRESH[1 - ks] : WCARR[9 - ks];            \
      a1.u = (10 - ks >= 7) ? WFRESH[3 - ks] : WCARR[11 - ks];          \
      a2.u = (12 - ks >= 7) ? WFRESH[5 - ks] : WCARR[13 - ks];          \
      a3.u = WFRESH[7 - ks];                                            \
      acc[F][0] = __builtin_amdgcn_mfma_f32_32x32x16_bf16(a0.s, bb.s, acc[F][0], 0, 0, 0); \
      acc[F][1] = __builtin_amdgcn_mfma_f32_32x32x16_bf16(a1.s, bb.s, acc[F][1], 0, 0, 0); \
      acc[F][2] = __builtin_amdgcn_mfma_f32_32x32x16_bf16(a2.s, bb.s, acc[F][2], 0, 0, 0); \
      acc[F][3] = __builtin_amdgcn_mfma_f32_32x32x16_bf16(a3.s, bb.s, acc[F][3], 0, 0, 0); \
    } }

#define STEP(DD, WFRESH, WCARR, HASF0) {                                \
    const int cw = (61 - (DD)) < 0 ? 0 : (61 - (DD));                   \
    const int offw = (((cw & 3) << 8) + 4 * lane + 4 * w) & 1023;       \
    *(uint*)(ringE + offw) = kE;                                        \
    *(uint*)(ringO + offw) = ALIGNB(kE, kM, 2);                         \
    const int cn = (60 - (DD)) < 0 ? 0 : (60 - (DD));                   \
    const uint kE2 = *(const uint*)(kr + cn * 128 + 2 * lane);          \
    const uint kM2 = *(const uint*)(kr + cn * 128 + 2 * lane - 2);      \
    _Pragma("unroll")                                                   \
    for (int i = 0; i < 8; ++i) {                                       \
      const int off = (bd - 224 - 32 * i) & 1023;                       \
      WFRESH[i] = *(const uint4*)(ringR + off);                         \
    }                                                                   \
    if (HASF0) { FPART(DD, 0, WFRESH, WCARR); FPART(DD, 1, WFRESH, WCARR); } \
    else { FPART(DD, 1, WFRESH, WCARR); }                               \
    kE = kE2; kM = kM2;                                                 \
    bd -= 256;                                                          \
    asm volatile("s_waitcnt lgkmcnt(0)" ::: "memory");                  \
    __builtin_amdgcn_s_barrier();                                       \
    __builtin_amdgcn_sched_barrier(0);                                  \
  }

  for (int dd = 0; dd < 32; dd += 2) {
    STEP(dd, WA, WB, true);
    STEP(dd + 1, WB, WA, true);
  }
  for (int dd = 32; dd < 64; dd += 2) {
    STEP(dd, WA, WB, false);
    STEP(dd + 1, WB, WA, false);
  }

  // ---- epilogue: += D*u, exact GELU, bf16 store ----
  const float Dh = Dp[h];
  ushort* gp = g + (((size_t)(w * HDIM + h)) << 13);
  const ushort* urow = Us + w * USTRIDE + 128;
#pragma unroll
  for (int f = 0; f < 2; ++f) {
#pragma unroll
    for (int rg = 0; rg < 4; ++rg) {
      const int lbase = (f * 32 + c32) * 128 + rg * 32 + 4 * qh;
#pragma unroll
      for (int rq = 0; rq < 4; ++rq) {
        const int l = lbase + 8 * rq;
        const int cI = l >> 3;
        const int phys = USWZ16(cI);
        const uint2 uv = *(const uint2*)(urow + (phys << 3) + 4 * qh);
        float uu[4];
        uu[0] = bf2f((ushort)(uv.x & 0xffff));
        uu[1] = bf2f((ushort)(uv.x >> 16));
        uu[2] = bf2f((ushort)(uv.y & 0xffff));
        uu[3] = bf2f((ushort)(uv.y >> 16));
        ushort o[4];
#pragma unroll
        for (int jj = 0; jj < 4; ++jj) {
          const float y = acc[f][rg][rq * 4 + jj] + Dh * uu[jj];
          const float ge = 0.5f * y * (1.0f + erff(y * 0.70710678118654752f));
          o[jj] = f2bf(ge);
        }
        uint2 op;
        op.x = (uint)o[0] | ((uint)o[1] << 16);
        op.y = (uint)o[2] | ((uint)o[3] << 16);
        *(uint2*)(gp + l) = op;
      }
    }
  }
}

// ---------------------------------------------------------------------------
// Kernel 3: transpose g[b][h][l] -> gt[b][l][h] (64x64 tiles, XOR-swizzled)
// ---------------------------------------------------------------------------
__global__ __launch_bounds__(256) void transpose_kernel(
    const ushort* __restrict__ g, ushort* __restrict__ gt) {
  __shared__ __align__(16) ushort Ts[64 * 64];
  const int l0 = blockIdx.x * 64, hh0 = blockIdx.y * 64, b = blockIdx.z;
  const int tid = threadIdx.x;
#pragma unroll
  for (int p = 0; p < 2; ++p) {
    const int hh = (tid >> 3) + 32 * p;
    const int c8 = tid & 7;
    const uint4 v = *(const uint4*)(g + (((size_t)(b * HDIM + hh0 + hh)) << 13)
                                    + l0 + c8 * 8);
    ((uint4*)Ts)[hh * 8 + (c8 ^ ((hh >> 3) & 7))] = v;
  }
  __syncthreads();
#pragma unroll
  for (int p = 0; p < 2; ++p) {
    const int lr = (tid >> 3) + 32 * p;
    const int o8 = tid & 7;
    U16 pk;
#pragma unroll
    for (int j = 0; j < 8; ++j) {
      const int hq = o8 * 8 + j;
      pk.e[j] = Ts[hq * 64 + (((lr >> 3) ^ o8) << 3) + (lr & 7)];
    }
    ((uint4*)(gt + ((size_t)b * LFULL + l0 + lr) * HDIM + hh0))[o8] = pk.u;
  }
}

// ---------------------------------------------------------------------------
// Kernel 4: W fp32 -> bf16
// ---------------------------------------------------------------------------
__global__ __launch_bounds__(256) void wcvt_kernel(const float* __restrict__ W,
                                                   ushort* __restrict__ Wb) {
  const int i = (blockIdx.x * 256 + threadIdx.x) * 8;
  const float4 v0 = *(const float4*)(W + i);
  const float4 v1 = *(const float4*)(W + i + 4);
  U16 pk;
  pk.e[0] = f2bf(v0.x); pk.e[1] = f2bf(v0.y);
  pk.e[2] = f2bf(v0.z); pk.e[3] = f2bf(v0.w);
  pk.e[4] = f2bf(v1.x); pk.e[5] = f2bf(v1.y);
  pk.e[6] = f2bf(v1.z); pk.e[7] = f2bf(v1.w);
  ((uint4*)Wb)[i >> 3] = pk.u;
}

// ---------------------------------------------------------------------------
// Kernel 5: out[b,o,l] = bo[o] + sum_h Wb[o,h]*gt[b,l,h]  (128x128 MFMA GEMM)
// BK=64 (16 kt iterations, half the barriers). T2 conflict fix: LDS rows are
// 128B; frag reads would be 8-16-way conflicted, so the k-chunk index is
// XOR-swizzled with (row&7) via PRE-SWIZZLED GLOBAL SOURCE (LDS dest stays
// lane-linear for global_load_lds); frag reads apply the same XOR -> <=2-way.
// ---------------------------------------------------------------------------
__global__ __launch_bounds__(256, 2) void outmm_kernel(
    const ushort* __restrict__ Wb, const ushort* __restrict__ gt,
    const float* __restrict__ bo, float* __restrict__ out) {
  __shared__ __align__(16) ushort As[128 * 64];
  __shared__ __align__(16) ushort Bs[128 * 64];
  const int tid = threadIdx.x;
  const int l0 = blockIdx.x * 128, o0 = blockIdx.y * 128, b = blockIdx.z;
  const int w = tid >> 6, lane = tid & 63;
  const int wm = w >> 1, wn = w & 1;
  const int col = lane & 15, q = lane >> 4;
  const int srow = tid >> 3;          // 0..31 (row mod 32 group)
  const int sch = tid & 7;            // 16B chunk 0..7 within row
  const int gch = sch ^ (srow & 7);   // pre-swizzled global chunk
  f32x4 acc[4][4];
#pragma unroll
  for (int m = 0; m < 4; ++m)
#pragma unroll
    for (int n = 0; n < 4; ++n) acc[m][n] = (f32x4){0.f, 0.f, 0.f, 0.f};
  const ushort* gb = gt + ((size_t)b * LFULL) * HDIM;
  for (int kt = 0; kt < 16; ++kt) {
    const int k0 = kt * 64;
#pragma unroll
    for (int ii = 0; ii < 4; ++ii) {
      const int row = srow + 32 * ii;
      gload16(Wb + (size_t)(o0 + row) * HDIM + k0 + gch * 8,
              As + row * 64 + sch * 8);
      gload16(gb + (size_t)(l0 + row) * HDIM + k0 + gch * 8,
              Bs + row * 64 + sch * 8);
    }
    __syncthreads();
    // frag reads: logical k-chunk (kk*4+q) lives at slot (kk*4+q)^(row&7);
    // row&7 == col&7 for both A and B rows.
    bf16x8 aa[2][4], bb[2][4];
#pragma unroll
    for (int kk = 0; kk < 2; ++kk)
#pragma unroll
      for (int m = 0; m < 4; ++m) {
        const int ra = wm * 64 + m * 16 + col;
        const int rb = wn * 64 + m * 16 + col;
        aa[kk][m] = ((const bf16x8*)As)[ra * 8 + ((kk * 4 + q) ^ (ra & 7))];
        bb[kk][m] = ((const bf16x8*)Bs)[rb * 8 + ((kk * 4 + q) ^ (rb & 7))];
      }
#pragma unroll
    for (int kk = 0; kk < 2; ++kk)
#pragma unroll
      for (int m = 0; m < 4; ++m)
#pragma unroll
        for (int n = 0; n < 4; ++n)
          acc[m][n] = __builtin_amdgcn_mfma_f32_16x16x32_bf16(
              aa[kk][m], bb[kk][n], acc[m][n], 0, 0, 0);
    __syncthreads();
  }
#pragma unroll
  for (int m = 0; m < 4; ++m) {
    const int ob = o0 + wm * 64 + m * 16 + q * 4;
    const float4 bv = *(const float4*)(bo + ob);
    const float bva[4] = {bv.x, bv.y, bv.z, bv.w};
#pragma unroll
    for (int n = 0; n < 4; ++n) {
      const int l = l0 + wn * 64 + n * 16 + col;
      float* op = out + (((size_t)(b * HDIM + ob)) << 13) + l;
#pragma unroll
      for (int v = 0; v < 4; ++v) op[(size_t)v << 13] = acc[m][n][v] + bva[v];
    }
  }
}

// ---------------------------------------------------------------------------
extern "C" void kernel_launch(void* const* d_in, const int* in_sizes, int n_in,
                              void* d_out, int out_size, void* d_ws,
                              size_t ws_size, hipStream_t stream) {
  const float* u = (const float*)d_in[0];     // (4, 1024, 8192)
  const float* kern = (const float*)d_in[1];  // (8, 1, 1024, 64)
  const float* D = (const float*)d_in[2];     // (1, 1024)
  const float* W = (const float*)d_in[3];     // (1024, 1024)
  const float* bo = (const float*)d_in[4];    // (1024,)
  float* out = (float*)d_out;                 // (4, 1024, 8192)

  char* ws = (char*)d_ws;
  ushort* g = (ushort*)ws;                                 // [0, 64 MiB)
  ushort* gt = (ushort*)(ws + ((size_t)64 << 20));         // [64, 128 MiB)
  ushort* kbrev = (ushort*)(ws + ((size_t)128 << 20));     // 1024*8448*2 = 16.5 MiB
  ushort* Wb = (ushort*)(ws + ((size_t)128 << 20));        // reuses kbrev region

  k_synth_kernel<<<HDIM, 256, 0, stream>>>(kern, kbrev);
  conv_mfma_kernel<<<HDIM, 256, 0, stream>>>(u, kbrev, D, g);
  // kbrev dead from here; Wb overlays it.
  wcvt_kernel<<<512, 256, 0, stream>>>(W, Wb);
  transpose_kernel<<<dim3(128, 16, 4), 256, 0, stream>>>(g, gt);
  outmm_kernel<<<dim3(64, 8, 4), 256, 0, stream>>>(Wb, gt, bo, out);
}

// Round 15
// 452.629 us; speedup vs baseline: 1.7224x; 1.0201x over previous
//
#include <hip/hip_runtime.h>
#include <hip/hip_bf16.h>

#define LFULL 8192
#define HDIM 1024
#define KPAD 8448  // 66 chunks of 128 elems (last 2 chunks zeros)
#define USTRIDE 8320   // elements per Us row: 128 zero-pad + 8192 data
#define UCHUNKS 1040   // uint4 chunks per Us row (= USTRIDE/8)
#define CSTRIDE 1040   // ring copy stride in bytes (1024 + 16 pad: 4-bank shift)

typedef __attribute__((ext_vector_type(8))) short bf16x8;
typedef __attribute__((ext_vector_type(4))) float f32x4;
typedef __attribute__((ext_vector_type(16))) float f32x16;

union U16 {
  uint4 u;
  bf16x8 s;
  ushort e[8];
};

__device__ __forceinline__ ushort f2bf(float x) {
  union { float f; uint u; } a;
  a.f = x;
  uint r = a.u + 0x7fffu + ((a.u >> 16) & 1u);
  return (ushort)(r >> 16);
}
__device__ __forceinline__ float bf2f(ushort x) {
  union { uint u; float f; } a;
  a.u = ((uint)x) << 16;
  return a.f;
}

__device__ __forceinline__ void gload16(const void* src, void* lds) {
  __builtin_amdgcn_global_load_lds(
      (const __attribute__((address_space(1))) unsigned int*)src,
      (__attribute__((address_space(3))) unsigned int*)lds, 16, 0, 0);
}

__device__ __forceinline__ uint ALIGNB(uint hi, uint lo, uint sh) {
#if __has_builtin(__builtin_amdgcn_alignbyte)
  return __builtin_amdgcn_alignbyte(hi, lo, sh);
#else
  return (uint)((((unsigned long long)hi << 32) | (unsigned long long)lo) >> (8u * sh));
#endif
}

// 4-bit XOR swizzle for Us 16B-chunk index (bijective: low4 ^= bits7:4)
#define USWZ16(cI) ((cI) ^ (((cI) >> 4) & 15))

// ---------------------------------------------------------------------------
// Kernel 1: multi-scale kernel synthesis + L2 norm -> bf16 kbrev[h][8448]
// kbrev[h][x] = k_norm[h][8191-x], zeros for x >= 8192.
// ---------------------------------------------------------------------------
__global__ __launch_bounds__(256) void k_synth_kernel(
    const float* __restrict__ kern, ushort* __restrict__ kout) {
  const int h = blockIdx.x;
  const int tid = threadIdx.x;
  __shared__ float Kw[8][64];
  __shared__ __align__(16) float kv[LFULL];
  __shared__ float red[8];
  for (int idx = tid; idx < 8 * 64; idx += 256) {
    int i = idx >> 6, j = idx & 63;
    Kw[i][j] = kern[(i * HDIM + h) * 64 + j];
  }
  __syncthreads();
  const float mult = (float)(1.0 + 3.0 * (double)h / 1023.0);
  float pw[8];
  pw[7] = 1.0f;
#pragma unroll
  for (int i = 6; i >= 0; --i) pw[i] = pw[i + 1] * mult;
  float ss = 0.0f;
  for (int m = tid; m < LFULL; m += 256) {
    const int i = (m < 64) ? 0 : (32 - __clz(m >> 6));
    const int slog = (i == 0) ? 0 : (i - 1);
    const float inv_s = 1.0f / (float)(1 << slog);
    const int off = (i == 0) ? 0 : (64 << (i - 1));
    const int t = m - off;
    const float pos = ((float)t + 0.5f) * inv_s - 0.5f;
    const float lof = floorf(pos);
    const float wgt = pos - lof;
    int lo = (int)lof;
    int hi = lo + 1;
    lo = min(63, max(0, lo));
    hi = min(63, max(0, hi));
    const float val = (Kw[i][lo] * (1.0f - wgt) + Kw[i][hi] * wgt) * pw[i];
    kv[m] = val;
    ss += val * val;
  }
#pragma unroll
  for (int o = 32; o > 0; o >>= 1) ss += __shfl_xor(ss, o, 64);
  if ((tid & 63) == 0) red[tid >> 6] = ss;
  __syncthreads();
  if (tid == 0) red[0] = sqrtf(red[0] + red[1] + red[2] + red[3]);
  __syncthreads();
  const float inv_norm = 1.0f / red[0];
  ushort* krow = kout + (size_t)h * KPAD;
  for (int m = tid; m < LFULL; m += 256) krow[8191 - m] = f2bf(kv[m] * inv_norm);
  if (tid < 256) krow[8192 + tid] = 0;
}

// ---------------------------------------------------------------------------
// Kernel 2: causal conv via block-Toeplitz 32x32x16 MFMA, T=128 blocks.
// EXACT R9 structure (best measured: 349 us, MfmaUtil 56%). Grid 1024 (1 h).
// Block: 4 waves (wave = b). acc = 2 F x 4 rg (128 AGPR). A-windows from a
// SHARED 8-phase-copy LDS ring (stride 1040 B, 4-bank shift per copy,
// conflict-free); window = ONE aligned ds_read_b128. Causal zeros via
// 128-elem zero pad before each Us row. WA/WB bank swap carries 6 windows.
// One lgkmcnt(0)+s_barrier per step.
// ---------------------------------------------------------------------------
__global__ __launch_bounds__(256, 2) void conv_mfma_kernel(
    const float* __restrict__ u, const ushort* __restrict__ kbrev,
    const float* __restrict__ Dp, ushort* __restrict__ g) {
  __shared__ __align__(16) ushort Us[4 * USTRIDE];   // 66.5 KB (pad+data x4)
  __shared__ __align__(16) ushort RingC[8 * 520];    // 8320 B: 8 phase copies
  const int tid = threadIdx.x;
  const int h = blockIdx.x;
  const int w = tid >> 6;  // wave index == b
  const int lane = tid & 63;
  const int c32 = lane & 31;
  const int qh = lane >> 5;
  uint4* Us4 = (uint4*)Us;
  char* ringB = (char*)RingC;
  const int wbase = w * UCHUNKS + 16;  // chunk base of row data (16 pad chunks)

  // ---- zero pads (4 rows x 16 chunks) ----
  if (tid < 64) Us4[(tid >> 4) * UCHUNKS + (tid & 15)] = make_uint4(0, 0, 0, 0);
  // ---- stage u: fp32 -> bf16, XOR16-swizzled 16B chunks (4 rows) ----
  for (int cc = tid; cc < 4096; cc += 256) {
    const int row = cc >> 10, cI = cc & 1023;
    const float* up = u + (((size_t)(row * HDIM + h)) << 13) + (cI << 3);
    const float4 v0 = *(const float4*)up;
    const float4 v1 = *(const float4*)(up + 4);
    U16 pk;
    pk.e[0] = f2bf(v0.x); pk.e[1] = f2bf(v0.y);
    pk.e[2] = f2bf(v0.z); pk.e[3] = f2bf(v0.w);
    pk.e[4] = f2bf(v1.x); pk.e[5] = f2bf(v1.y);
    pk.e[6] = f2bf(v1.z); pk.e[7] = f2bf(v1.w);
    Us4[(row * UCHUNKS + 16) + USWZ16(cI)] = pk.u;
  }

  // ---- ring prologue: preload chunks 62,63,64 into copies 2w, 2w+1 ----
  const ushort* kr = kbrev + (size_t)h * KPAD;
  char* ringE = ringB + (2 * w) * CSTRIDE;
  char* ringO = ringB + (2 * w + 1) * CSTRIDE;
#pragma unroll
  for (int cn = 62; cn <= 64; ++cn) {
    const int x0 = 128 * cn + 2 * lane;
    const uint kEp = *(const uint*)(kr + x0);
    const uint kMp = *(const uint*)(kr + x0 - 2);
    const int off = (2 * x0 + 4 * w) & 1023;
    *(uint*)(ringE + off) = kEp;
    *(uint*)(ringO + off) = ALIGNB(kEp, kMp, 2);
  }
  // prefetch chunk 61 (written at step 0)
  uint kE = *(const uint*)(kr + 61 * 128 + 2 * lane);
  uint kM = *(const uint*)(kr + 61 * 128 + 2 * lane - 2);
  __syncthreads();

  f32x16 acc[2][4];
#pragma unroll
  for (int f = 0; f < 2; ++f)
#pragma unroll
    for (int rg = 0; rg < 4; ++rg)
#pragma unroll
      for (int q = 0; q < 16; ++q) acc[f][rg][q] = 0.0f;

  const int PBASE = 8191 - c32 + 8 * qh;
  const int sph = (c32 + 1) & 7;            // lane's phase copy
  const char* ringR = ringB + sph * CSTRIDE;
  int bd = 2 * (PBASE + sph) + 256;         // off(d,mm) = (bd - 32mm) & 1023

  uint4 WA[8], WB[8];
#pragma unroll
  for (int i = 0; i < 8; ++i) WB[i] = make_uint4(0, 0, 0, 0);

// carried(mm<7) lives in the OTHER bank at [mm+1]; fresh(mm>=7) at [mm-7]
#define FPART(DD, F, WFRESH, WCARR) {                                   \
    const int j0 = (F) * 32 + c32 - (DD);                               \
    const int jc = j0 < 0 ? -1 : j0;                                    \
    const int pb = jc << 4;                                             \
    const int px = jc & 15;                                             \
    _Pragma("unroll")                                                   \
    for (int ks = 0; ks < 8; ++ks) {                                    \
      const int t = 2 * ks + qh;                                        \
      U16 bb;                                                           \
      bb.u = Us4[wbase + pb + (t ^ px)];                                \
      U16 a0, a1, a2, a3;                                               \
      a0.u = (8 - ks >= 7) ? WFRESH[1 - ks] : WCARR[9 - ks];            \
      a1.u = (10 - ks >= 7) ? WFRESH[3 - ks] : WCARR[11 - ks];          \
      a2.u = (12 - ks >= 7) ? WFRESH[5 - ks] : WCARR[13 - ks];          \
      a3.u = WFRESH[7 - ks];                                            \
      acc[F][0] = __builtin_amdgcn_mfma_f32_32x32x16_bf16(a0.s, bb.s, acc[F][0], 0, 0, 0); \
      acc[F][1] = __builtin_amdgcn_mfma_f32_32x32x16_bf16(a1.s, bb.s, acc[F][1], 0, 0, 0); \
      acc[F][2] = __builtin_amdgcn_mfma_f32_32x32x16_bf16(a2.s, bb.s, acc[F][2], 0, 0, 0); \
      acc[F][3] = __builtin_amdgcn_mfma_f32_32x32x16_bf16(a3.s, bb.s, acc[F][3], 0, 0, 0); \
    } }

#define STEP(DD, WFRESH, WCARR, HASF0) {                                \
    const int cw = (61 - (DD)) < 0 ? 0 : (61 - (DD));                   \
    const int offw = (((cw & 3) << 8) + 4 * lane + 4 * w) & 1023;       \
    *(uint*)(ringE + offw) = kE;                                        \
    *(uint*)(ringO + offw) = ALIGNB(kE, kM, 2);                         \
    const int cn = (60 - (DD)) < 0 ? 0 : (60 - (DD));                   \
    const uint kE2 = *(const uint*)(kr + cn * 128 + 2 * lane);          \
    const uint kM2 = *(const uint*)(kr + cn * 128 + 2 * lane - 2);      \
    _Pragma("unroll")                                                   \
    for (int i = 0; i < 8; ++i) {                                       \
      const int off = (bd - 224 - 32 * i) & 1023;                       \
      WFRESH[i] = *(const uint4*)(ringR + off);                         \
    }                                                                   \
    if (HASF0) { FPART(DD, 0, WFRESH, WCARR); FPART(DD, 1, WFRESH, WCARR); } \
    else { FPART(DD, 1, WFRESH, WCARR); }                               \
    kE = kE2; kM = kM2;                                                 \
    bd -= 256;                                                          \
    asm volatile("s_waitcnt lgkmcnt(0)" ::: "memory");                  \
    __builtin_amdgcn_s_barrier();                                       \
    __builtin_amdgcn_sched_barrier(0);                                  \
  }

  for (int dd = 0; dd < 32; dd += 2) {
    STEP(dd, WA, WB, true);
    STEP(dd + 1, WB, WA, true);
  }
  for (int dd = 32; dd < 64; dd += 2) {
    STEP(dd, WA, WB, false);
    STEP(dd + 1, WB, WA, false);
  }

  // ---- epilogue: += D*u, exact GELU, bf16 store ----
  const float Dh = Dp[h];
  ushort* gp = g + (((size_t)(w * HDIM + h)) << 13);
  const ushort* urow = Us + w * USTRIDE + 128;
#pragma unroll
  for (int f = 0; f < 2; ++f) {
#pragma unroll
    for (int rg = 0; rg < 4; ++rg) {
      const int lbase = (f * 32 + c32) * 128 + rg * 32 + 4 * qh;
#pragma unroll
      for (int rq = 0; rq < 4; ++rq) {
        const int l = lbase + 8 * rq;
        const int cI = l >> 3;
        const int phys = USWZ16(cI);
        const uint2 uv = *(const uint2*)(urow + (phys << 3) + 4 * qh);
        float uu[4];
        uu[0] = bf2f((ushort)(uv.x & 0xffff));
        uu[1] = bf2f((ushort)(uv.x >> 16));
        uu[2] = bf2f((ushort)(uv.y & 0xffff));
        uu[3] = bf2f((ushort)(uv.y >> 16));
        ushort o[4];
#pragma unroll
        for (int jj = 0; jj < 4; ++jj) {
          const float y = acc[f][rg][rq * 4 + jj] + Dh * uu[jj];
          const float ge = 0.5f * y * (1.0f + erff(y * 0.70710678118654752f));
          o[jj] = f2bf(ge);
        }
        uint2 op;
        op.x = (uint)o[0] | ((uint)o[1] << 16);
        op.y = (uint)o[2] | ((uint)o[3] << 16);
        *(uint2*)(gp + l) = op;
      }
    }
  }
}

// ---------------------------------------------------------------------------
// Kernel 3: transpose g[b][h][l] -> gt[b][l][h] (64x64 tiles, XOR-swizzled)
// ---------------------------------------------------------------------------
__global__ __launch_bounds__(256) void transpose_kernel(
    const ushort* __restrict__ g, ushort* __restrict__ gt) {
  __shared__ __align__(16) ushort Ts[64 * 64];
  const int l0 = blockIdx.x * 64, hh0 = blockIdx.y * 64, b = blockIdx.z;
  const int tid = threadIdx.x;
#pragma unroll
  for (int p = 0; p < 2; ++p) {
    const int hh = (tid >> 3) + 32 * p;
    const int c8 = tid & 7;
    const uint4 v = *(const uint4*)(g + (((size_t)(b * HDIM + hh0 + hh)) << 13)
                                    + l0 + c8 * 8);
    ((uint4*)Ts)[hh * 8 + (c8 ^ ((hh >> 3) & 7))] = v;
  }
  __syncthreads();
#pragma unroll
  for (int p = 0; p < 2; ++p) {
    const int lr = (tid >> 3) + 32 * p;
    const int o8 = tid & 7;
    U16 pk;
#pragma unroll
    for (int j = 0; j < 8; ++j) {
      const int hq = o8 * 8 + j;
      pk.e[j] = Ts[hq * 64 + (((lr >> 3) ^ o8) << 3) + (lr & 7)];
    }
    ((uint4*)(gt + ((size_t)b * LFULL + l0 + lr) * HDIM + hh0))[o8] = pk.u;
  }
}

// ---------------------------------------------------------------------------
// Kernel 4: W fp32 -> bf16
// ---------------------------------------------------------------------------
__global__ __launch_bounds__(256) void wcvt_kernel(const float* __restrict__ W,
                                                   ushort* __restrict__ Wb) {
  const int i = (blockIdx.x * 256 + threadIdx.x) * 8;
  const float4 v0 = *(const float4*)(W + i);
  const float4 v1 = *(const float4*)(W + i + 4);
  U16 pk;
  pk.e[0] = f2bf(v0.x); pk.e[1] = f2bf(v0.y);
  pk.e[2] = f2bf(v0.z); pk.e[3] = f2bf(v0.w);
  pk.e[4] = f2bf(v1.x); pk.e[5] = f2bf(v1.y);
  pk.e[6] = f2bf(v1.z); pk.e[7] = f2bf(v1.w);
  ((uint4*)Wb)[i >> 3] = pk.u;
}

// ---------------------------------------------------------------------------
// Kernel 5: out[b,o,l] = bo[o] + sum_h Wb[o,h]*gt[b,l,h]
// 256(o) x 128(l) MFMA GEMM, BK=64, 512 thr (8 waves: wm=w>>1 o-quadrant,
// wn=w&1 l-half; per-wave 64x64). A-panel reuse x2 vs 128^2 (staging
// bytes/FLOP -25%), blocks halved -> barrier overhead per FLOP halved.
// T2 conflict fix kept: pre-swizzled global source chunk (LDS dest linear
// for global_load_lds), frag reads XOR the same (row&7).
// ---------------------------------------------------------------------------
__global__ __launch_bounds__(512, 4) void outmm_kernel(
    const ushort* __restrict__ Wb, const ushort* __restrict__ gt,
    const float* __restrict__ bo, float* __restrict__ out) {
  __shared__ __align__(16) ushort As[256 * 64];  // 32 KB
  __shared__ __align__(16) ushort Bs[128 * 64];  // 16 KB
  const int tid = threadIdx.x;
  const int l0 = blockIdx.x * 128, o0 = blockIdx.y * 256, b = blockIdx.z;
  const int w = tid >> 6, lane = tid & 63;
  const int wm = w >> 1, wn = w & 1;
  const int col = lane & 15, q = lane >> 4;
  const int srow = tid >> 3;          // 0..63 (row group)
  const int sch = tid & 7;            // 16B chunk 0..7 within row
  const int gch = sch ^ (srow & 7);   // pre-swizzled global chunk
  f32x4 acc[4][4];
#pragma unroll
  for (int m = 0; m < 4; ++m)
#pragma unroll
    for (int n = 0; n < 4; ++n) acc[m][n] = (f32x4){0.f, 0.f, 0.f, 0.f};
  const ushort* gb = gt + ((size_t)b * LFULL) * HDIM;
  for (int kt = 0; kt < 16; ++kt) {
    const int k0 = kt * 64;
#pragma unroll
    for (int ii = 0; ii < 4; ++ii) {
      const int row = srow + 64 * ii;
      gload16(Wb + (size_t)(o0 + row) * HDIM + k0 + gch * 8,
              As + row * 64 + sch * 8);
    }
#pragma unroll
    for (int jj = 0; jj < 2; ++jj) {
      const int row = srow + 64 * jj;
      gload16(gb + (size_t)(l0 + row) * HDIM + k0 + gch * 8,
              Bs + row * 64 + sch * 8);
    }
    __syncthreads();
    // frag reads: logical k-chunk (kk*4+q) lives at slot (kk*4+q)^(row&7);
    // row&7 == col&7 for both A and B rows.
    bf16x8 aa[2][4], bb[2][4];
#pragma unroll
    for (int kk = 0; kk < 2; ++kk)
#pragma unroll
      for (int m = 0; m < 4; ++m) {
        const int ra = wm * 64 + m * 16 + col;
        const int rb = wn * 64 + m * 16 + col;
        aa[kk][m] = ((const bf16x8*)As)[ra * 8 + ((kk * 4 + q) ^ (ra & 7))];
        bb[kk][m] = ((const bf16x8*)Bs)[rb * 8 + ((kk * 4 + q) ^ (rb & 7))];
      }
#pragma unroll
    for (int kk = 0; kk < 2; ++kk)
#pragma unroll
      for (int m = 0; m < 4; ++m)
#pragma unroll
        for (int n = 0; n < 4; ++n)
          acc[m][n] = __builtin_amdgcn_mfma_f32_16x16x32_bf16(
              aa[kk][m], bb[kk][n], acc[m][n], 0, 0, 0);
    __syncthreads();
  }
#pragma unroll
  for (int m = 0; m < 4; ++m) {
    const int ob = o0 + wm * 64 + m * 16 + q * 4;
    const float4 bv = *(const float4*)(bo + ob);
    const float bva[4] = {bv.x, bv.y, bv.z, bv.w};
#pragma unroll
    for (int n = 0; n < 4; ++n) {
      const int l = l0 + wn * 64 + n * 16 + col;
      float* op = out + (((size_t)(b * HDIM + ob)) << 13) + l;
#pragma unroll
      for (int v = 0; v < 4; ++v) op[(size_t)v << 13] = acc[m][n][v] + bva[v];
    }
  }
}

// ---------------------------------------------------------------------------
extern "C" void kernel_launch(void* const* d_in, const int* in_sizes, int n_in,
                              void* d_out, int out_size, void* d_ws,
                              size_t ws_size, hipStream_t stream) {
  const float* u = (const float*)d_in[0];     // (4, 1024, 8192)
  const float* kern = (const float*)d_in[1];  // (8, 1, 1024, 64)
  const float* D = (const float*)d_in[2];     // (1, 1024)
  const float* W = (const float*)d_in[3];     // (1024, 1024)
  const float* bo = (const float*)d_in[4];    // (1024,)
  float* out = (float*)d_out;                 // (4, 1024, 8192)

  char* ws = (char*)d_ws;
  ushort* g = (ushort*)ws;                                 // [0, 64 MiB)
  ushort* gt = (ushort*)(ws + ((size_t)64 << 20));         // [64, 128 MiB)
  ushort* kbrev = (ushort*)(ws + ((size_t)128 << 20));     // 1024*8448*2 = 16.5 MiB
  ushort* Wb = (ushort*)(ws + ((size_t)128 << 20));        // reuses kbrev region

  k_synth_kernel<<<HDIM, 256, 0, stream>>>(kern, kbrev);
  conv_mfma_kernel<<<HDIM, 256, 0, stream>>>(u, kbrev, D, g);
  // kbrev dead from here; Wb overlays it.
  wcvt_kernel<<<512, 256, 0, stream>>>(W, Wb);
  transpose_kernel<<<dim3(128, 16, 4), 256, 0, stream>>>(g, gt);
  outmm_kernel<<<dim3(64, 4, 4), 512, 0, stream>>>(Wb, gt, bo, out);
}